// Round 13
// baseline (250.593 us; speedup 1.0000x reference)
//
#include <hip/hip_runtime.h>
#include <cstdint>

#define EDIM 1024
#define NHEADS 16
#define HDIM 64
#define BATCH 2
#define SEQ 2048
#define MROWS (BATCH * SEQ) // 4096

typedef __attribute__((ext_vector_type(8))) short bf16x8; // 8 bf16 = 4 VGPR
typedef __attribute__((ext_vector_type(4))) float f32x4;

// Q pre-scale: (1/sqrt(64)) * log2(e)  -> softmax runs in exp2 domain
#define QSCALE 0.18033688011112042f

__device__ __forceinline__ unsigned short f2bf(float f) {
  union { float f; unsigned u; } v; v.f = f;
  unsigned r = v.u + 0x7FFFu + ((v.u >> 16) & 1u); // RNE
  return (unsigned short)(r >> 16);
}

// pack two f32 -> two bf16 (RNE): D[15:0]=lo, D[31:16]=hi
__device__ __forceinline__ unsigned cvt_pk_bf16(float lo, float hi) {
  unsigned r;
  asm("v_cvt_pk_bf16_f32 %0, %1, %2" : "=v"(r) : "v"(lo), "v"(hi));
  return r;
}

// async global -> LDS, 16 B per lane (dest = wave-uniform base + lane*16)
__device__ __forceinline__ void gload16(const void* g, void* l) {
  __builtin_amdgcn_global_load_lds(
      (const __attribute__((address_space(1))) unsigned int*)g,
      (__attribute__((address_space(3))) unsigned int*)l, 16, 0, 0);
}

// ---------------------------------------------------------------------------
// fused fp32 -> bf16 convert for x, W_qkv, W_proj in ONE launch
// ---------------------------------------------------------------------------
__global__ __launch_bounds__(256) void cvt_all_kernel(
    const float* __restrict__ x, const float* __restrict__ wq,
    const float* __restrict__ wp, unsigned short* __restrict__ xo,
    unsigned short* __restrict__ wqo, unsigned short* __restrict__ wpo) {
  const int NX = MROWS * EDIM, NQ = 3 * EDIM * EDIM, NP = EDIM * EDIM;
  int i = (blockIdx.x * 256 + threadIdx.x) * 8;
  const float* src;
  unsigned short* dst;
  if (i < NX) {
    src = x + i; dst = xo + i;
  } else if (i < NX + NQ) {
    src = wq + (i - NX); dst = wqo + (i - NX);
  } else if (i < NX + NQ + NP) {
    src = wp + (i - NX - NQ); dst = wpo + (i - NX - NQ);
  } else {
    return;
  }
  const float4 a = *(const float4*)&src[0];
  const float4 b = *(const float4*)&src[4];
  unsigned u[4];
  u[0] = cvt_pk_bf16(a.x, a.y);
  u[1] = cvt_pk_bf16(a.z, a.w);
  u[2] = cvt_pk_bf16(b.x, b.y);
  u[3] = cvt_pk_bf16(b.z, b.w);
  *(uint4*)dst = *(uint4*)u;
}

// ---------------------------------------------------------------------------
// bf16 MFMA GEMM NT: C = A @ W^T + bias. BK=64, linear LDS + global_load_lds.
// MODE 0: 128x128 tile (grid 24x32), scatter Q(*QSCALE)/K/V -> [B,H,S,D].
// MODE 1: 64x128 tile (grid 8x64 = 512 blocks -> 2 blocks/CU), +resid, fp32.
// Both: bijective XCD-aware swizzle, column stripes per XCD (W panel cached).
// ---------------------------------------------------------------------------
template <int MODE>
__global__ __launch_bounds__(256) void gemm_bf16(
    const unsigned short* __restrict__ A, const unsigned short* __restrict__ Bw,
    const float* __restrict__ bias, const float* __restrict__ resid,
    unsigned short* __restrict__ q_out, unsigned short* __restrict__ k_out,
    unsigned short* __restrict__ v_out, float* __restrict__ y_out,
    int M, int N, int K) {
  constexpr int BM = (MODE == 0) ? 128 : 64;  // rows per block
  constexpr int IR = BM / 32;                 // acc row-frags per wave (4 / 2)
  __shared__ unsigned short As[BM * 64]; // linear [row][k] (gload_lds dest)
  __shared__ unsigned short Bs[128 * 64];
  const int tid = threadIdx.x;
  const int lane = tid & 63, w = tid >> 6;
  const int wr = w >> 1, wc = w & 1;
  const int l15 = lane & 15, g = lane >> 4;

  // XCD-aware bijective remap (8 XCDs own column stripes):
  const int flat = blockIdx.y * gridDim.x + blockIdx.x;
  const int xk = flat & 7, xi = flat >> 3;
  int bx, by;
  if (MODE == 0) { bx = xk * 3 + (xi >> 5); by = xi & 31; } // 768 = 8*3*32
  else           { bx = xk;                 by = xi; }      // 512 = 8*64
  const int row0 = by * BM, col0 = bx * 128;

  // staging map: instr t covers rows w*(BM/4)+t*8+(lane>>3), col (lane&7)*8
  const int erA = w * (BM / 4) + (lane >> 3);
  const int erB = w * 32 + (lane >> 3);
  const int ec = (lane & 7) * 8;

  f32x4 acc[IR][4];
#pragma unroll
  for (int i = 0; i < IR; ++i)
#pragma unroll
    for (int j = 0; j < 4; ++j) acc[i][j] = (f32x4){0.f, 0.f, 0.f, 0.f};

  for (int k0 = 0; k0 < K; k0 += 64) {
    __syncthreads(); // prior-iter frag reads complete before overwrite
#pragma unroll
    for (int t = 0; t < BM / 32; ++t)
      gload16(&A[(size_t)(row0 + erA + t * 8) * K + k0 + ec],
              &As[w * (BM * 16) + t * 512]);
#pragma unroll
    for (int t = 0; t < 4; ++t)
      gload16(&Bw[(size_t)(col0 + erB + t * 8) * K + k0 + ec],
              &Bs[w * 2048 + t * 512]);
    __syncthreads(); // drains vmcnt: staged tile visible
#pragma unroll
    for (int ks = 0; ks < 2; ++ks) {
      bf16x8 af[IR], bfr[4];
#pragma unroll
      for (int i = 0; i < IR; ++i)
        af[i] = *(const bf16x8*)&As[(wr * (BM / 2) + i * 16 + l15) * 64 +
                                    ks * 32 + g * 8];
#pragma unroll
      for (int j = 0; j < 4; ++j)
        bfr[j] = *(const bf16x8*)&Bs[(wc * 64 + j * 16 + l15) * 64 + ks * 32 + g * 8];
#pragma unroll
      for (int i = 0; i < IR; ++i)
#pragma unroll
        for (int j = 0; j < 4; ++j)
          acc[i][j] = __builtin_amdgcn_mfma_f32_16x16x32_bf16(af[i], bfr[j],
                                                              acc[i][j], 0, 0, 0);
    }
  }

#pragma unroll
  for (int j = 0; j < 4; ++j) {
    const int nbase = col0 + wc * 64 + j * 16 + l15;
    const float bb = bias[nbase];
#pragma unroll
    for (int i = 0; i < IR; ++i) {
#pragma unroll
      for (int r = 0; r < 4; ++r) {
        const int m = row0 + wr * (BM / 2) + i * 16 + g * 4 + r;
        float v = acc[i][j][r] + bb;
        if (MODE == 0) {
          const int which = nbase >> 10;
          const int h = (nbase >> 6) & 15, d = nbase & 63;
          const int b = m >> 11, s = m & 2047;
          const size_t idx = ((size_t)(b * NHEADS + h) * SEQ + s) * HDIM + d;
          if (which == 0) q_out[idx] = f2bf(v * QSCALE); // fold scale*log2e
          else if (which == 1) k_out[idx] = f2bf(v);
          else v_out[idx] = f2bf(v);
        } else {
          v += resid[(size_t)m * N + nbase];
          y_out[(size_t)m * N + nbase] = v;
        }
      }
    }
  }
}

// ---------------------------------------------------------------------------
// V [B,H,S,D] -> Vt [B,H,D,S] tile transpose (64 s-rows per block)
// ---------------------------------------------------------------------------
__global__ __launch_bounds__(256) void vtrans_kernel(
    const unsigned short* __restrict__ V, unsigned short* __restrict__ Vt) {
  __shared__ unsigned short T[64 * 72];
  const int tid = threadIdx.x;
  const int st = blockIdx.x, bh = blockIdx.y;
  const size_t ibase = (size_t)bh * SEQ * HDIM + (size_t)st * 64 * HDIM;
#pragma unroll
  for (int t = 0; t < 2; ++t) {
    const int chunk = t * 256 + tid; // 512 chunks of 16B
    const int r = chunk >> 3, c8 = chunk & 7;
    const uint4 v = *(const uint4*)&V[ibase + r * 64 + c8 * 8];
    *(uint4*)&T[r * 72 + c8 * 8] = v;
  }
  __syncthreads();
  const size_t obase = (size_t)bh * HDIM * SEQ + st * 64;
#pragma unroll
  for (int t = 0; t < 2; ++t) {
    const int chunk = t * 256 + tid;
    const int d = chunk >> 3, s8 = (chunk & 7) * 8;
    unsigned short u[8];
#pragma unroll
    for (int e = 0; e < 8; ++e) u[e] = T[(s8 + e) * 72 + d];
    *(uint4*)&Vt[obase + (size_t)d * SEQ + s8] = *(uint4*)u;
  }
}

// ---------------------------------------------------------------------------
// Flash attention — round-10 structure restored (best measured: 70.3 us),
// only delta vs r10: softmax in exp2 domain (Q pre-scaled by QSCALE upstream).
// No XCD swizzle, no ones-MFMA, no defer-max (r11/r12 regressions reverted).
// 8 waves x 16 q-rows = QBLK 128, KV tile 64, K/V^T in LDS (dbuf, XOR-swz,
// global_load_lds), 1 barrier per tile, P in [q][80] layout.
// ---------------------------------------------------------------------------
__global__ __launch_bounds__(512, 4) void attn_mfma(
    const unsigned short* __restrict__ Qb, const unsigned short* __restrict__ Kb,
    const unsigned short* __restrict__ Vt, unsigned short* __restrict__ AO) {
  __shared__ unsigned short K_lds[2][64 * 64]; // [kv][d], swizzled cols, 16KB
  __shared__ unsigned short V_lds[2][64 * 64]; // [d][s],  swizzled cols, 16KB
  __shared__ unsigned short P_lds[128 * 80];   // [q][kv] bf16, pad 80, 20KB
  const int tid = threadIdx.x;
  const int lane = tid & 63, w = tid >> 6; // 8 waves
  const int l15 = lane & 15, g = lane >> 4;
  const int qt = blockIdx.x; // 16
  const int bh = blockIdx.y; // 32
  const int b = bh >> 4, h = bh & 15;
  const size_t hbase = (size_t)bh * SEQ * HDIM;
  const size_t vbase = (size_t)bh * HDIM * SEQ;
  const int q = qt * 128 + w * 16 + l15; // this lane's q row
  const int prow = (w * 16 + l15) * 80;  // P_lds row (wave-private span)

  // staging geometry: waves 0-3 stage K rows, waves 4-7 stage V(d) rows
  const int sr = (w & 3) * 16 + (lane >> 3);
  const int scol = ((lane & 7) ^ (lane >> 3)) * 8; // pre-swizzled source col

  bf16x8 aq[2];
#pragma unroll
  for (int ks = 0; ks < 2; ++ks)
    aq[ks] = *(const bf16x8*)&Qb[hbase + (size_t)q * HDIM + ks * 32 + g * 8];

  f32x4 o[4];
#pragma unroll
  for (int jd = 0; jd < 4; ++jd) o[jd] = (f32x4){0.f, 0.f, 0.f, 0.f};
  float mi = -1e30f, li = 0.f;

#define STAGE(buf, kt_)                                                        \
  do {                                                                         \
    if (w < 4) {                                                               \
      gload16(&Kb[hbase + (size_t)((kt_) * 64 + sr) * HDIM + scol],            \
              &K_lds[buf][(w * 16) * 64]);                                     \
      gload16(&Kb[hbase + (size_t)((kt_) * 64 + sr + 8) * HDIM + scol],        \
              &K_lds[buf][(w * 16 + 8) * 64]);                                 \
    } else {                                                                   \
      gload16(&Vt[vbase + (size_t)sr * SEQ + (kt_) * 64 + scol],               \
              &V_lds[buf][((w - 4) * 16) * 64]);                               \
      gload16(&Vt[vbase + (size_t)(sr + 8) * SEQ + (kt_) * 64 + scol],         \
              &V_lds[buf][((w - 4) * 16 + 8) * 64]);                           \
    }                                                                          \
  } while (0)

  STAGE(0, 0);
  for (int kt = 0; kt < SEQ / 64; ++kt) {
    const int cur = kt & 1;
    __syncthreads(); // drains vmcnt (buf[cur] ready) + prior reads of buf[cur^1]
    if (kt + 1 < SEQ / 64) STAGE(cur ^ 1, kt + 1); // async, overlaps compute

    // ---- QK^T (swapped): sc_T[j] row=kv, col=q; scores in log2 domain ----
    f32x4 scT[4];
#pragma unroll
    for (int j = 0; j < 4; ++j) scT[j] = (f32x4){0.f, 0.f, 0.f, 0.f};
    __builtin_amdgcn_s_setprio(1);
#pragma unroll
    for (int ks = 0; ks < 2; ++ks) {
      bf16x8 bk[4];
#pragma unroll
      for (int j = 0; j < 4; ++j)
        bk[j] = *(const bf16x8*)&K_lds[cur][(j * 16 + l15) * 64 +
                                            (((ks * 4 + g) ^ (l15 & 7)) * 8)];
#pragma unroll
      for (int j = 0; j < 4; ++j)
        scT[j] = __builtin_amdgcn_mfma_f32_16x16x32_bf16(bk[j], aq[ks],
                                                         scT[j], 0, 0, 0);
    }
    __builtin_amdgcn_s_setprio(0);

    // ---- online softmax (exp2 domain): lane owns q=l15, 16 kv values ----
    float tm = scT[0][0];
#pragma unroll
    for (int j = 0; j < 4; ++j)
#pragma unroll
      for (int r = 0; r < 4; ++r) tm = fmaxf(tm, scT[j][r]);
    tm = fmaxf(tm, __shfl_xor(tm, 16));
    tm = fmaxf(tm, __shfl_xor(tm, 32));
    const float mn = fmaxf(mi, tm);
    const float al = exp2f(mi - mn);
    mi = mn;
    float p[4][4];
    float rs = 0.f;
#pragma unroll
    for (int j = 0; j < 4; ++j)
#pragma unroll
      for (int r = 0; r < 4; ++r) {
        p[j][r] = exp2f(scT[j][r] - mn);
        rs += p[j][r];
      }
    rs += __shfl_xor(rs, 16);
    rs += __shfl_xor(rs, 32);
    li = li * al + rs;
    // P -> LDS [q][kv], packed b32 writes
#pragma unroll
    for (int j = 0; j < 4; ++j) {
      *(unsigned*)&P_lds[prow + j * 16 + g * 4 + 0] = cvt_pk_bf16(p[j][0], p[j][1]);
      *(unsigned*)&P_lds[prow + j * 16 + g * 4 + 2] = cvt_pk_bf16(p[j][2], p[j][3]);
    }
    // rescale O (alpha is lane-local)
#pragma unroll
    for (int jd = 0; jd < 4; ++jd)
#pragma unroll
      for (int r = 0; r < 4; ++r) o[jd][r] *= al;

    // ---- PV (swapped): o[jd] row=d, col=q ----
    __builtin_amdgcn_s_setprio(1);
#pragma unroll
    for (int ks = 0; ks < 2; ++ks) {
      const bf16x8 ap = *(const bf16x8*)&P_lds[prow + ks * 32 + g * 8];
      bf16x8 bv[4];
#pragma unroll
      for (int jd = 0; jd < 4; ++jd)
        bv[jd] = *(const bf16x8*)&V_lds[cur][(jd * 16 + l15) * 64 +
                                             (((ks * 4 + g) ^ (l15 & 7)) * 8)];
#pragma unroll
      for (int jd = 0; jd < 4; ++jd)
        o[jd] = __builtin_amdgcn_mfma_f32_16x16x32_bf16(bv[jd], ap, o[jd], 0, 0, 0);
    }
    __builtin_amdgcn_s_setprio(0);
  }
#undef STAGE

  // epilogue: lane holds O[d = jd*16+g*4+r][q=l15] -> 8B stores
  const float inv = 1.f / li;
#pragma unroll
  for (int jd = 0; jd < 4; ++jd) {
    uint2 u;
    u.x = cvt_pk_bf16(o[jd][0] * inv, o[jd][1] * inv);
    u.y = cvt_pk_bf16(o[jd][2] * inv, o[jd][3] * inv);
    *(uint2*)&AO[(size_t)(b * SEQ + q) * EDIM + h * HDIM + jd * 16 + g * 4] = u;
  }
}

// ---------------------------------------------------------------------------
// In-place LayerNorm over E=1024, eps=1e-5
// ---------------------------------------------------------------------------
__global__ __launch_bounds__(256) void ln_kernel(float* __restrict__ y,
                                                 const float* __restrict__ gamma,
                                                 const float* __restrict__ beta) {
  const int row = blockIdx.x, tid = threadIdx.x;
  const float4 v = *reinterpret_cast<const float4*>(&y[(size_t)row * EDIM + tid * 4]);
  float s = v.x + v.y + v.z + v.w;
  float s2 = v.x * v.x + v.y * v.y + v.z * v.z + v.w * v.w;
#pragma unroll
  for (int off = 1; off < 64; off <<= 1) {
    s += __shfl_xor(s, off);
    s2 += __shfl_xor(s2, off);
  }
  __shared__ float red[8];
  if ((tid & 63) == 0) {
    red[(tid >> 6) * 2 + 0] = s;
    red[(tid >> 6) * 2 + 1] = s2;
  }
  __syncthreads();
  s = red[0] + red[2] + red[4] + red[6];
  s2 = red[1] + red[3] + red[5] + red[7];
  const float mean = s * (1.f / 1024.f);
  const float var = fmaxf(s2 * (1.f / 1024.f) - mean * mean, 0.f);
  const float rstd = rsqrtf(var + 1e-5f);
  const float4 gm = *reinterpret_cast<const float4*>(&gamma[tid * 4]);
  const float4 be = *reinterpret_cast<const float4*>(&beta[tid * 4]);
  float4 outv;
  outv.x = (v.x - mean) * rstd * gm.x + be.x;
  outv.y = (v.y - mean) * rstd * gm.y + be.y;
  outv.z = (v.z - mean) * rstd * gm.z + be.z;
  outv.w = (v.w - mean) * rstd * gm.w + be.w;
  *reinterpret_cast<float4*>(&y[(size_t)row * EDIM + tid * 4]) = outv;
}

extern "C" void kernel_launch(void* const* d_in, const int* in_sizes, int n_in,
                              void* d_out, int out_size, void* d_ws,
                              size_t ws_size, hipStream_t stream) {
  const float* x = (const float*)d_in[0];
  const float* W_qkv = (const float*)d_in[1];
  const float* b_qkv = (const float*)d_in[2];
  const float* W_proj = (const float*)d_in[3];
  const float* b_proj = (const float*)d_in[4];
  const float* gamma = (const float*)d_in[5];
  const float* beta = (const float*)d_in[6];
  float* out = (float*)d_out;

  uint8_t* p = (uint8_t*)d_ws;
  unsigned short* x_bf = (unsigned short*)p;            p += (size_t)MROWS * EDIM * 2;      // 8 MB
  unsigned short* wqkv_bf = (unsigned short*)p;         p += (size_t)3 * EDIM * EDIM * 2;   // 6 MB
  unsigned short* wproj_bf = (unsigned short*)p;        p += (size_t)EDIM * EDIM * 2;       // 2 MB
  unsigned short* Qb = (unsigned short*)p;              p += (size_t)MROWS * EDIM * 2;      // 8 MB
  unsigned short* Kb = (unsigned short*)p;              p += (size_t)MROWS * EDIM * 2;      // 8 MB
  unsigned short* Vb = (unsigned short*)p;              p += (size_t)MROWS * EDIM * 2;      // 8 MB
  unsigned short* Vtb = (unsigned short*)p;             p += (size_t)MROWS * EDIM * 2;      // 8 MB
  unsigned short* AOb = (unsigned short*)p;             p += (size_t)MROWS * EDIM * 2;      // 8 MB

  // fused fp32 -> bf16 converts (one launch)
  const int NCVT = MROWS * EDIM + 3 * EDIM * EDIM + EDIM * EDIM;
  cvt_all_kernel<<<(NCVT / 8 + 255) / 256, 256, 0, stream>>>(
      x, W_qkv, W_proj, x_bf, wqkv_bf, wproj_bf);

  // QKV projection -> Q(*QSCALE)/K/V [B,H,S,D]
  gemm_bf16<0><<<dim3(24, 32), 256, 0, stream>>>(x_bf, wqkv_bf, b_qkv, nullptr,
                                                 Qb, Kb, Vb, nullptr,
                                                 MROWS, 3 * EDIM, EDIM);
  // V -> V^T [B,H,D,S]
  vtrans_kernel<<<dim3(SEQ / 64, BATCH * NHEADS), 256, 0, stream>>>(Vb, Vtb);
  // flash attention -> AO bf16 [B,S,E]
  attn_mfma<<<dim3(SEQ / 128, BATCH * NHEADS), 512, 0, stream>>>(Qb, Kb, Vtb, AOb);
  // out projection + bias + residual -> fp32 y (64x128 tiles, 512 blocks)
  gemm_bf16<1><<<dim3(8, 64), 256, 0, stream>>>(AOb, wproj_bf, b_proj, x,
                                                nullptr, nullptr, nullptr, out,
                                                MROWS, EDIM, EDIM);
  // in-place LayerNorm
  ln_kernel<<<MROWS, 256, 0, stream>>>(out, gamma, beta);
}

// Round 14
// 238.307 us; speedup vs baseline: 1.0516x; 1.0516x over previous
//
#include <hip/hip_runtime.h>
#include <cstdint>

#define EDIM 1024
#define NHEADS 16
#define HDIM 64
#define BATCH 2
#define SEQ 2048
#define MROWS (BATCH * SEQ) // 4096

typedef __attribute__((ext_vector_type(8))) short bf16x8; // 8 bf16 = 4 VGPR
typedef __attribute__((ext_vector_type(4))) float f32x4;

__device__ __forceinline__ unsigned short f2bf(float f) {
  union { float f; unsigned u; } v; v.f = f;
  unsigned r = v.u + 0x7FFFu + ((v.u >> 16) & 1u); // RNE
  return (unsigned short)(r >> 16);
}

// pack two f32 -> two bf16 (RNE): D[15:0]=lo, D[31:16]=hi
__device__ __forceinline__ unsigned cvt_pk_bf16(float lo, float hi) {
  unsigned r;
  asm("v_cvt_pk_bf16_f32 %0, %1, %2" : "=v"(r) : "v"(lo), "v"(hi));
  return r;
}

// async global -> LDS, 16 B per lane (dest = wave-uniform base + lane*16)
__device__ __forceinline__ void gload16(const void* g, void* l) {
  __builtin_amdgcn_global_load_lds(
      (const __attribute__((address_space(1))) unsigned int*)g,
      (__attribute__((address_space(3))) unsigned int*)l, 16, 0, 0);
}

// ---------------------------------------------------------------------------
// fused fp32 -> bf16 convert for x, W_qkv, W_proj in ONE launch
// ---------------------------------------------------------------------------
__global__ __launch_bounds__(256) void cvt_all_kernel(
    const float* __restrict__ x, const float* __restrict__ wq,
    const float* __restrict__ wp, unsigned short* __restrict__ xo,
    unsigned short* __restrict__ wqo, unsigned short* __restrict__ wpo) {
  const int NX = MROWS * EDIM, NQ = 3 * EDIM * EDIM, NP = EDIM * EDIM;
  int i = (blockIdx.x * 256 + threadIdx.x) * 8;
  const float* src;
  unsigned short* dst;
  if (i < NX) {
    src = x + i; dst = xo + i;
  } else if (i < NX + NQ) {
    src = wq + (i - NX); dst = wqo + (i - NX);
  } else if (i < NX + NQ + NP) {
    src = wp + (i - NX - NQ); dst = wpo + (i - NX - NQ);
  } else {
    return;
  }
  const float4 a = *(const float4*)&src[0];
  const float4 b = *(const float4*)&src[4];
  unsigned u[4];
  u[0] = cvt_pk_bf16(a.x, a.y);
  u[1] = cvt_pk_bf16(a.z, a.w);
  u[2] = cvt_pk_bf16(b.x, b.y);
  u[3] = cvt_pk_bf16(b.z, b.w);
  *(uint4*)dst = *(uint4*)u;
}

// ---------------------------------------------------------------------------
// bf16 MFMA GEMM NT: C = A @ W^T + bias. BK=64, linear LDS + global_load_lds.
// MODE 0: 128x128 tile (grid 24x32), scatter Q(*0.125)/K/V -> [B,H,S,D].
// MODE 1: 64x128 tile (grid 8x64 = 512 blocks -> 2 blocks/CU), +resid, fp32.
// Both: bijective XCD-aware swizzle, column stripes per XCD (W panel cached).
// ---------------------------------------------------------------------------
template <int MODE>
__global__ __launch_bounds__(256) void gemm_bf16(
    const unsigned short* __restrict__ A, const unsigned short* __restrict__ Bw,
    const float* __restrict__ bias, const float* __restrict__ resid,
    unsigned short* __restrict__ q_out, unsigned short* __restrict__ k_out,
    unsigned short* __restrict__ v_out, float* __restrict__ y_out,
    int M, int N, int K) {
  constexpr int BM = (MODE == 0) ? 128 : 64;  // rows per block
  constexpr int IR = BM / 32;                 // acc row-frags per wave (4 / 2)
  __shared__ unsigned short As[BM * 64]; // linear [row][k] (gload_lds dest)
  __shared__ unsigned short Bs[128 * 64];
  const int tid = threadIdx.x;
  const int lane = tid & 63, w = tid >> 6;
  const int wr = w >> 1, wc = w & 1;
  const int l15 = lane & 15, g = lane >> 4;

  // XCD-aware bijective remap (8 XCDs own column stripes):
  const int flat = blockIdx.y * gridDim.x + blockIdx.x;
  const int xk = flat & 7, xi = flat >> 3;
  int bx, by;
  if (MODE == 0) { bx = xk * 3 + (xi >> 5); by = xi & 31; } // 768 = 8*3*32
  else           { bx = xk;                 by = xi; }      // 512 = 8*64
  const int row0 = by * BM, col0 = bx * 128;

  // staging map: instr t covers rows w*(BM/4)+t*8+(lane>>3), col (lane&7)*8
  const int erA = w * (BM / 4) + (lane >> 3);
  const int erB = w * 32 + (lane >> 3);
  const int ec = (lane & 7) * 8;

  f32x4 acc[IR][4];
#pragma unroll
  for (int i = 0; i < IR; ++i)
#pragma unroll
    for (int j = 0; j < 4; ++j) acc[i][j] = (f32x4){0.f, 0.f, 0.f, 0.f};

  for (int k0 = 0; k0 < K; k0 += 64) {
    __syncthreads(); // prior-iter frag reads complete before overwrite
#pragma unroll
    for (int t = 0; t < BM / 32; ++t)
      gload16(&A[(size_t)(row0 + erA + t * 8) * K + k0 + ec],
              &As[w * (BM * 16) + t * 512]);
#pragma unroll
    for (int t = 0; t < 4; ++t)
      gload16(&Bw[(size_t)(col0 + erB + t * 8) * K + k0 + ec],
              &Bs[w * 2048 + t * 512]);
    __syncthreads(); // drains vmcnt: staged tile visible
#pragma unroll
    for (int ks = 0; ks < 2; ++ks) {
      bf16x8 af[IR], bfr[4];
#pragma unroll
      for (int i = 0; i < IR; ++i)
        af[i] = *(const bf16x8*)&As[(wr * (BM / 2) + i * 16 + l15) * 64 +
                                    ks * 32 + g * 8];
#pragma unroll
      for (int j = 0; j < 4; ++j)
        bfr[j] = *(const bf16x8*)&Bs[(wc * 64 + j * 16 + l15) * 64 + ks * 32 + g * 8];
#pragma unroll
      for (int i = 0; i < IR; ++i)
#pragma unroll
        for (int j = 0; j < 4; ++j)
          acc[i][j] = __builtin_amdgcn_mfma_f32_16x16x32_bf16(af[i], bfr[j],
                                                              acc[i][j], 0, 0, 0);
    }
  }

#pragma unroll
  for (int j = 0; j < 4; ++j) {
    const int nbase = col0 + wc * 64 + j * 16 + l15;
    const float bb = bias[nbase];
#pragma unroll
    for (int i = 0; i < IR; ++i) {
#pragma unroll
      for (int r = 0; r < 4; ++r) {
        const int m = row0 + wr * (BM / 2) + i * 16 + g * 4 + r;
        float v = acc[i][j][r] + bb;
        if (MODE == 0) {
          const int which = nbase >> 10;
          const int h = (nbase >> 6) & 15, d = nbase & 63;
          const int b = m >> 11, s = m & 2047;
          const size_t idx = ((size_t)(b * NHEADS + h) * SEQ + s) * HDIM + d;
          if (which == 0) q_out[idx] = f2bf(v * 0.125f); // fold 1/sqrt(D)
          else if (which == 1) k_out[idx] = f2bf(v);
          else v_out[idx] = f2bf(v);
        } else {
          v += resid[(size_t)m * N + nbase];
          y_out[(size_t)m * N + nbase] = v;
        }
      }
    }
  }
}

// ---------------------------------------------------------------------------
// V [B,H,S,D] -> Vt [B,H,D,S] tile transpose (64 s-rows per block)
// ---------------------------------------------------------------------------
__global__ __launch_bounds__(256) void vtrans_kernel(
    const unsigned short* __restrict__ V, unsigned short* __restrict__ Vt) {
  __shared__ unsigned short T[64 * 72];
  const int tid = threadIdx.x;
  const int st = blockIdx.x, bh = blockIdx.y;
  const size_t ibase = (size_t)bh * SEQ * HDIM + (size_t)st * 64 * HDIM;
#pragma unroll
  for (int t = 0; t < 2; ++t) {
    const int chunk = t * 256 + tid; // 512 chunks of 16B
    const int r = chunk >> 3, c8 = chunk & 7;
    const uint4 v = *(const uint4*)&V[ibase + r * 64 + c8 * 8];
    *(uint4*)&T[r * 72 + c8 * 8] = v;
  }
  __syncthreads();
  const size_t obase = (size_t)bh * HDIM * SEQ + st * 64;
#pragma unroll
  for (int t = 0; t < 2; ++t) {
    const int chunk = t * 256 + tid;
    const int d = chunk >> 3, s8 = (chunk & 7) * 8;
    unsigned short u[8];
#pragma unroll
    for (int e = 0; e < 8; ++e) u[e] = T[(s8 + e) * 72 + d];
    *(uint4*)&Vt[obase + (size_t)d * SEQ + s8] = *(uint4*)u;
  }
}

// ---------------------------------------------------------------------------
// Flash attention — exact round-10 kernel (best measured: 70.3 us).
// __expf softmax (fast-math intrinsic -> v_mul+v_exp; exp2f was the OCML
// library call and cost +13 us, r13 lesson). Q pre-scaled by 0.125 upstream.
// 8 waves x 16 q-rows = QBLK 128, KV tile 64, K/V^T in LDS (dbuf, XOR-swz,
// global_load_lds), 1 barrier per tile, P in [q][80] layout.
// ---------------------------------------------------------------------------
__global__ __launch_bounds__(512, 4) void attn_mfma(
    const unsigned short* __restrict__ Qb, const unsigned short* __restrict__ Kb,
    const unsigned short* __restrict__ Vt, unsigned short* __restrict__ AO) {
  __shared__ unsigned short K_lds[2][64 * 64]; // [kv][d], swizzled cols, 16KB
  __shared__ unsigned short V_lds[2][64 * 64]; // [d][s],  swizzled cols, 16KB
  __shared__ unsigned short P_lds[128 * 80];   // [q][kv] bf16, pad 80, 20KB
  const int tid = threadIdx.x;
  const int lane = tid & 63, w = tid >> 6; // 8 waves
  const int l15 = lane & 15, g = lane >> 4;
  const int qt = blockIdx.x; // 16
  const int bh = blockIdx.y; // 32
  const int b = bh >> 4, h = bh & 15;
  const size_t hbase = (size_t)bh * SEQ * HDIM;
  const size_t vbase = (size_t)bh * HDIM * SEQ;
  const int q = qt * 128 + w * 16 + l15; // this lane's q row
  const int prow = (w * 16 + l15) * 80;  // P_lds row (wave-private span)

  // staging geometry: waves 0-3 stage K rows, waves 4-7 stage V(d) rows
  const int sr = (w & 3) * 16 + (lane >> 3);
  const int scol = ((lane & 7) ^ (lane >> 3)) * 8; // pre-swizzled source col

  bf16x8 aq[2];
#pragma unroll
  for (int ks = 0; ks < 2; ++ks)
    aq[ks] = *(const bf16x8*)&Qb[hbase + (size_t)q * HDIM + ks * 32 + g * 8];

  f32x4 o[4];
#pragma unroll
  for (int jd = 0; jd < 4; ++jd) o[jd] = (f32x4){0.f, 0.f, 0.f, 0.f};
  float mi = -1e30f, li = 0.f;

#define STAGE(buf, kt_)                                                        \
  do {                                                                         \
    if (w < 4) {                                                               \
      gload16(&Kb[hbase + (size_t)((kt_) * 64 + sr) * HDIM + scol],            \
              &K_lds[buf][(w * 16) * 64]);                                     \
      gload16(&Kb[hbase + (size_t)((kt_) * 64 + sr + 8) * HDIM + scol],        \
              &K_lds[buf][(w * 16 + 8) * 64]);                                 \
    } else {                                                                   \
      gload16(&Vt[vbase + (size_t)sr * SEQ + (kt_) * 64 + scol],               \
              &V_lds[buf][((w - 4) * 16) * 64]);                               \
      gload16(&Vt[vbase + (size_t)(sr + 8) * SEQ + (kt_) * 64 + scol],         \
              &V_lds[buf][((w - 4) * 16 + 8) * 64]);                           \
    }                                                                          \
  } while (0)

  STAGE(0, 0);
  for (int kt = 0; kt < SEQ / 64; ++kt) {
    const int cur = kt & 1;
    __syncthreads(); // drains vmcnt (buf[cur] ready) + prior reads of buf[cur^1]
    if (kt + 1 < SEQ / 64) STAGE(cur ^ 1, kt + 1); // async, overlaps compute

    // ---- QK^T (swapped): sc_T[j] row=kv, col=q ----
    f32x4 scT[4];
#pragma unroll
    for (int j = 0; j < 4; ++j) scT[j] = (f32x4){0.f, 0.f, 0.f, 0.f};
    __builtin_amdgcn_s_setprio(1);
#pragma unroll
    for (int ks = 0; ks < 2; ++ks) {
      bf16x8 bk[4];
#pragma unroll
      for (int j = 0; j < 4; ++j)
        bk[j] = *(const bf16x8*)&K_lds[cur][(j * 16 + l15) * 64 +
                                            (((ks * 4 + g) ^ (l15 & 7)) * 8)];
#pragma unroll
      for (int j = 0; j < 4; ++j)
        scT[j] = __builtin_amdgcn_mfma_f32_16x16x32_bf16(bk[j], aq[ks],
                                                         scT[j], 0, 0, 0);
    }
    __builtin_amdgcn_s_setprio(0);

    // ---- online softmax: lane owns q=l15, 16 kv values (j*16+g*4+r) ----
    float tm = scT[0][0];
#pragma unroll
    for (int j = 0; j < 4; ++j)
#pragma unroll
      for (int r = 0; r < 4; ++r) tm = fmaxf(tm, scT[j][r]);
    tm = fmaxf(tm, __shfl_xor(tm, 16));
    tm = fmaxf(tm, __shfl_xor(tm, 32));
    const float mn = fmaxf(mi, tm);
    const float al = __expf(mi - mn);
    mi = mn;
    float p[4][4];
    float rs = 0.f;
#pragma unroll
    for (int j = 0; j < 4; ++j)
#pragma unroll
      for (int r = 0; r < 4; ++r) {
        p[j][r] = __expf(scT[j][r] - mn);
        rs += p[j][r];
      }
    rs += __shfl_xor(rs, 16);
    rs += __shfl_xor(rs, 32);
    li = li * al + rs;
    // P -> LDS [q][kv], packed b32 writes
#pragma unroll
    for (int j = 0; j < 4; ++j) {
      *(unsigned*)&P_lds[prow + j * 16 + g * 4 + 0] = cvt_pk_bf16(p[j][0], p[j][1]);
      *(unsigned*)&P_lds[prow + j * 16 + g * 4 + 2] = cvt_pk_bf16(p[j][2], p[j][3]);
    }
    // rescale O (alpha is lane-local)
#pragma unroll
    for (int jd = 0; jd < 4; ++jd)
#pragma unroll
      for (int r = 0; r < 4; ++r) o[jd][r] *= al;

    // ---- PV (swapped): o[jd] row=d, col=q ----
    __builtin_amdgcn_s_setprio(1);
#pragma unroll
    for (int ks = 0; ks < 2; ++ks) {
      const bf16x8 ap = *(const bf16x8*)&P_lds[prow + ks * 32 + g * 8];
      bf16x8 bv[4];
#pragma unroll
      for (int jd = 0; jd < 4; ++jd)
        bv[jd] = *(const bf16x8*)&V_lds[cur][(jd * 16 + l15) * 64 +
                                             (((ks * 4 + g) ^ (l15 & 7)) * 8)];
#pragma unroll
      for (int jd = 0; jd < 4; ++jd)
        o[jd] = __builtin_amdgcn_mfma_f32_16x16x32_bf16(bv[jd], ap, o[jd], 0, 0, 0);
    }
    __builtin_amdgcn_s_setprio(0);
  }
#undef STAGE

  // epilogue: lane holds O[d = jd*16+g*4+r][q=l15] -> 8B stores
  const float inv = 1.f / li;
#pragma unroll
  for (int jd = 0; jd < 4; ++jd) {
    uint2 u;
    u.x = cvt_pk_bf16(o[jd][0] * inv, o[jd][1] * inv);
    u.y = cvt_pk_bf16(o[jd][2] * inv, o[jd][3] * inv);
    *(uint2*)&AO[(size_t)(b * SEQ + q) * EDIM + h * HDIM + jd * 16 + g * 4] = u;
  }
}

// ---------------------------------------------------------------------------
// In-place LayerNorm over E=1024, eps=1e-5
// ---------------------------------------------------------------------------
__global__ __launch_bounds__(256) void ln_kernel(float* __restrict__ y,
                                                 const float* __restrict__ gamma,
                                                 const float* __restrict__ beta) {
  const int row = blockIdx.x, tid = threadIdx.x;
  const float4 v = *reinterpret_cast<const float4*>(&y[(size_t)row * EDIM + tid * 4]);
  float s = v.x + v.y + v.z + v.w;
  float s2 = v.x * v.x + v.y * v.y + v.z * v.z + v.w * v.w;
#pragma unroll
  for (int off = 1; off < 64; off <<= 1) {
    s += __shfl_xor(s, off);
    s2 += __shfl_xor(s2, off);
  }
  __shared__ float red[8];
  if ((tid & 63) == 0) {
    red[(tid >> 6) * 2 + 0] = s;
    red[(tid >> 6) * 2 + 1] = s2;
  }
  __syncthreads();
  s = red[0] + red[2] + red[4] + red[6];
  s2 = red[1] + red[3] + red[5] + red[7];
  const float mean = s * (1.f / 1024.f);
  const float var = fmaxf(s2 * (1.f / 1024.f) - mean * mean, 0.f);
  const float rstd = rsqrtf(var + 1e-5f);
  const float4 gm = *reinterpret_cast<const float4*>(&gamma[tid * 4]);
  const float4 be = *reinterpret_cast<const float4*>(&beta[tid * 4]);
  float4 outv;
  outv.x = (v.x - mean) * rstd * gm.x + be.x;
  outv.y = (v.y - mean) * rstd * gm.y + be.y;
  outv.z = (v.z - mean) * rstd * gm.z + be.z;
  outv.w = (v.w - mean) * rstd * gm.w + be.w;
  *reinterpret_cast<float4*>(&y[(size_t)row * EDIM + tid * 4]) = outv;
}

extern "C" void kernel_launch(void* const* d_in, const int* in_sizes, int n_in,
                              void* d_out, int out_size, void* d_ws,
                              size_t ws_size, hipStream_t stream) {
  const float* x = (const float*)d_in[0];
  const float* W_qkv = (const float*)d_in[1];
  const float* b_qkv = (const float*)d_in[2];
  const float* W_proj = (const float*)d_in[3];
  const float* b_proj = (const float*)d_in[4];
  const float* gamma = (const float*)d_in[5];
  const float* beta = (const float*)d_in[6];
  float* out = (float*)d_out;

  uint8_t* p = (uint8_t*)d_ws;
  unsigned short* x_bf = (unsigned short*)p;            p += (size_t)MROWS * EDIM * 2;      // 8 MB
  unsigned short* wqkv_bf = (unsigned short*)p;         p += (size_t)3 * EDIM * EDIM * 2;   // 6 MB
  unsigned short* wproj_bf = (unsigned short*)p;        p += (size_t)EDIM * EDIM * 2;       // 2 MB
  unsigned short* Qb = (unsigned short*)p;              p += (size_t)MROWS * EDIM * 2;      // 8 MB
  unsigned short* Kb = (unsigned short*)p;              p += (size_t)MROWS * EDIM * 2;      // 8 MB
  unsigned short* Vb = (unsigned short*)p;              p += (size_t)MROWS * EDIM * 2;      // 8 MB
  unsigned short* Vtb = (unsigned short*)p;             p += (size_t)MROWS * EDIM * 2;      // 8 MB
  unsigned short* AOb = (unsigned short*)p;             p += (size_t)MROWS * EDIM * 2;      // 8 MB

  // fused fp32 -> bf16 converts (one launch)
  const int NCVT = MROWS * EDIM + 3 * EDIM * EDIM + EDIM * EDIM;
  cvt_all_kernel<<<(NCVT / 8 + 255) / 256, 256, 0, stream>>>(
      x, W_qkv, W_proj, x_bf, wqkv_bf, wproj_bf);

  // QKV projection -> Q(*0.125)/K/V [B,H,S,D]
  gemm_bf16<0><<<dim3(24, 32), 256, 0, stream>>>(x_bf, wqkv_bf, b_qkv, nullptr,
                                                 Qb, Kb, Vb, nullptr,
                                                 MROWS, 3 * EDIM, EDIM);
  // V -> V^T [B,H,D,S]
  vtrans_kernel<<<dim3(SEQ / 64, BATCH * NHEADS), 256, 0, stream>>>(Vb, Vtb);
  // flash attention -> AO bf16 [B,S,E]
  attn_mfma<<<dim3(SEQ / 128, BATCH * NHEADS), 512, 0, stream>>>(Qb, Kb, Vtb, AOb);
  // out projection + bias + residual -> fp32 y (64x128 tiles, 512 blocks)
  gemm_bf16<1><<<dim3(8, 64), 256, 0, stream>>>(AOb, wproj_bf, b_proj, x,
                                                nullptr, nullptr, nullptr, out,
                                                MROWS, EDIM, EDIM);
  // in-place LayerNorm
  ln_kernel<<<MROWS, 256, 0, stream>>>(out, gamma, beta);
}